// Round 11
// baseline (376.860 us; speedup 1.0000x reference)
//
#include <hip/hip_runtime.h>
#include <math.h>

#define N_NODES 50000
#define P_PATHS 4
#define E_EDGES 800000
#define IN_F 256
#define OUT_F 128
#define NPB 128                        // nodes per bucket
#define NBUCK 391                      // ceil(N/NPB)
#define NCHUNK 200                     // edge chunks per path
#define CHUNK_E (E_EDGES / NCHUNK)     // 4000
#define GBLK 391                       // row-blocks for gemm/fc (128 rows each)
#define DSL 20                         // edge slices for deg-out histogram
#define QTR 4                          // node quarters
#define Q_N 12500                      // nodes per quarter
#define Q_W 6250                       // packed u32 words per quarter (25KB LDS)
#define BKP 72                         // LDS pitch (u16) for BK=64 gemm tiles
#define FP 136                         // LDS pitch (u16) for K=128 tiles
#define RSB 196                        // rsout blocks in merged rsout+bscan

typedef unsigned short ushort_t;
typedef unsigned int uint_t;
typedef float f32x4 __attribute__((ext_vector_type(4)));
typedef short s16x8 __attribute__((ext_vector_type(8)));

__device__ __forceinline__ ushort_t f2bf(float f) {
    uint_t u = __float_as_uint(f);
    return (ushort_t)((u + 0x7FFFu + ((u >> 16) & 1u)) >> 16);   // RNE
}
__device__ __forceinline__ float bf2f(ushort_t h) {
    return __uint_as_float(((uint_t)h) << 16);
}
__device__ __forceinline__ uint4 pack8(const float4 f0, const float4 f1) {
    uint4 w;
    w.x = (uint_t)f2bf(f0.x) | ((uint_t)f2bf(f0.y) << 16);
    w.y = (uint_t)f2bf(f0.z) | ((uint_t)f2bf(f0.w) << 16);
    w.z = (uint_t)f2bf(f1.x) | ((uint_t)f2bf(f1.y) << 16);
    w.w = (uint_t)f2bf(f1.z) | ((uint_t)f2bf(f1.w) << 16);
    return w;
}
__device__ __forceinline__ float fast_tanh(float v) {
    v = fminf(fmaxf(v, -20.f), 20.f);
    float ex = __expf(2.f * v);
    return (ex - 1.f) / (ex + 1.f);
}
__device__ __forceinline__ void acc8(float4& a0, float4& a1, uint4 w) {
    a0.x += bf2f((ushort_t)w.x);  a0.y += bf2f((ushort_t)(w.x >> 16));
    a0.z += bf2f((ushort_t)w.y);  a0.w += bf2f((ushort_t)(w.y >> 16));
    a1.x += bf2f((ushort_t)w.z);  a1.y += bf2f((ushort_t)(w.z >> 16));
    a1.z += bf2f((ushort_t)w.w);  a1.w += bf2f((ushort_t)(w.w >> 16));
}

// ---------------- deg_out hist (q<QTR) + dst bucket hist (q==QTR) + prep (q==QTR+1) ----------------
__global__ __launch_bounds__(256) void deghist_kernel(const int* __restrict__ src,
                                                      const int* __restrict__ dst,
                                                      uint_t* __restrict__ dhist,
                                                      uint_t* __restrict__ bcounts,
                                                      const float* __restrict__ W,
                                                      const float* __restrict__ fcw,
                                                      ushort_t* __restrict__ Wt,
                                                      ushort_t* __restrict__ fcwb)
{
    __shared__ uint_t cnt[Q_W];   // 25 KB
    int sl = blockIdx.x, q = blockIdx.y, p = blockIdx.z;
    int t = threadIdx.x;
    if (q == QTR + 1) {
        // prep: W -> Wt bf16 transposed, fc_w -> bf16
        int g = (p * DSL + sl) * 256 + t;
        for (int idx = g; idx < P_PATHS * IN_F * OUT_F; idx += DSL * P_PATHS * 256) {
            int pp = idx >> 15;
            int r = idx & 32767;
            int k = r >> 7;
            int n = r & 127;
            Wt[((size_t)pp << 15) + (size_t)n * IN_F + k] = f2bf(W[idx]);
        }
        for (int idx = g; idx < OUT_F * OUT_F; idx += DSL * P_PATHS * 256)
            fcwb[idx] = f2bf(fcw[idx]);
        return;
    }
    if (q == QTR) {
        for (int i = t; i < NBUCK; i += 256) cnt[i] = 0;
        __syncthreads();
        const int4* d4 = (const int4*)(dst + (size_t)p * E_EDGES + (size_t)sl * (E_EDGES / DSL));
        for (int i = t; i < E_EDGES / DSL / 4; i += 256) {
            int4 v = d4[i];
            atomicAdd(&cnt[v.x >> 7], 1u);
            atomicAdd(&cnt[v.y >> 7], 1u);
            atomicAdd(&cnt[v.z >> 7], 1u);
            atomicAdd(&cnt[v.w >> 7], 1u);
        }
        __syncthreads();
        for (int i = t; i < NBUCK; i += 256)
            if (cnt[i]) atomicAdd(&bcounts[p * NBUCK + i], cnt[i]);
        return;
    }
    int nbase = q * Q_N;
    for (int i = t; i < Q_W; i += 256) cnt[i] = 0;
    __syncthreads();
    const int4* s4 = (const int4*)(src + (size_t)p * E_EDGES + (size_t)sl * (E_EDGES / DSL));
    for (int i = t; i < E_EDGES / DSL / 4; i += 256) {
        int4 v = s4[i];
        uint_t r;
        r = (uint_t)(v.x - nbase); if (r < Q_N) atomicAdd(&cnt[r >> 1], 1u << ((r & 1) * 16));
        r = (uint_t)(v.y - nbase); if (r < Q_N) atomicAdd(&cnt[r >> 1], 1u << ((r & 1) * 16));
        r = (uint_t)(v.z - nbase); if (r < Q_N) atomicAdd(&cnt[r >> 1], 1u << ((r & 1) * 16));
        r = (uint_t)(v.w - nbase); if (r < Q_N) atomicAdd(&cnt[r >> 1], 1u << ((r & 1) * 16));
    }
    __syncthreads();
    uint_t* outp = dhist + (((size_t)p * QTR + q) * DSL + sl) * Q_W;
    for (int i = t; i < Q_W; i += 256) outp[i] = cnt[i];
}

// ---------------- merged: blocks 0..RSB-1 -> rsout; block RSB -> bucket scan ----------------
__global__ __launch_bounds__(1024) void rsout_bscan_kernel(const uint_t* __restrict__ dhist,
                                                           float* __restrict__ rsout,
                                                           const uint_t* __restrict__ bcounts,
                                                           int* __restrict__ bstart,
                                                           int* __restrict__ bcursor)
{
    int t = threadIdx.x;
    if (blockIdx.x == RSB) {
        __shared__ int a[2048], b[2048];
        for (int i = t; i < 2048; i += 1024)
            a[i] = (i < P_PATHS * NBUCK) ? (int)bcounts[i] : 0;
        __syncthreads();
        int* pin = a; int* pout = b;
        for (int off = 1; off < 2048; off <<= 1) {
            for (int i = t; i < 2048; i += 1024)
                pout[i] = pin[i] + (i >= off ? pin[i - off] : 0);
            __syncthreads();
            int* tmp = pin; pin = pout; pout = tmp;
        }
        for (int i = t; i < P_PATHS * NBUCK; i += 1024) {
            int st = pin[i] - (int)bcounts[i];
            bstart[i] = st;
            bcursor[i] = st;
        }
        if (t == 0) bstart[P_PATHS * NBUCK] = pin[P_PATHS * NBUCK - 1];
        return;
    }
    int idx = blockIdx.x * 1024 + t;      // over P*QTR*Q_W
    if (idx >= P_PATHS * QTR * Q_W) return;
    int ph = idx / Q_W;
    int w  = idx % Q_W;
    const uint_t* base = dhist + (size_t)ph * DSL * Q_W + w;
    uint_t s = 0;
#pragma unroll
    for (int sl = 0; sl < DSL; ++sl) s += base[(size_t)sl * Q_W];
    int p = ph >> 2, q = ph & 3;
    int node = q * Q_N + 2 * w;
    uint_t c0 = s & 0xFFFFu, c1 = s >> 16;
    rsout[(size_t)p * N_NODES + node]     = rsqrtf((float)(c0 ? c0 : 1u));
    rsout[(size_t)p * N_NODES + node + 1] = rsqrtf((float)(c1 ? c1 : 1u));
}

// ---------------- MFMA GEMM, BK=64 tiles, path-pair per block ----------------
__global__ __launch_bounds__(256) void gemm_xall_kernel(const float* __restrict__ x,
                                                        const ushort_t* __restrict__ Wt,
                                                        const float* __restrict__ rsout,
                                                        ushort_t* __restrict__ xwb)
{
    __shared__ ushort_t As[128 * BKP];   // 18.4 KB
    __shared__ ushort_t Bs[128 * BKP];   // 18.4 KB
    int m0 = blockIdx.x * 128;
    int t = threadIdx.x;
    int wid = t >> 6, lane = t & 63;
    int wr = wid >> 1, wc = wid & 1;
    int srow = t >> 1, h32 = (t & 1) * 32;
    int gr = m0 + srow;
    for (int pp = 0; pp < 2; ++pp) {
        int p = blockIdx.y * 2 + pp;
        const ushort_t* Wp = Wt + ((size_t)p << 15);
        f32x4 acc[4][4] = {};
        for (int kt = 0; kt < 4; ++kt) {
            __syncthreads();   // prior tile reads done
            {   // A: 128x64 fp32 -> bf16
                const float* ap = x + (size_t)gr * IN_F + kt * 64 + h32;
#pragma unroll
                for (int c = 0; c < 4; ++c) {
                    float4 f0 = make_float4(0.f, 0.f, 0.f, 0.f), f1 = f0;
                    if (gr < N_NODES) {
                        f0 = *(const float4*)(ap + c * 8);
                        f1 = *(const float4*)(ap + c * 8 + 4);
                    }
                    *(uint4*)&As[srow * BKP + h32 + c * 8] = pack8(f0, f1);
                }
            }
            {   // B: Wt rows direct u16 copy
                const ushort_t* bp = Wp + (size_t)srow * IN_F + kt * 64 + h32;
#pragma unroll
                for (int c = 0; c < 4; ++c)
                    *(uint4*)&Bs[srow * BKP + h32 + c * 8] = *(const uint4*)(bp + c * 8);
            }
            __syncthreads();
#pragma unroll
            for (int k0 = 0; k0 < 64; k0 += 32) {
                s16x8 aF[4], bF[4];
                int kk = k0 + (lane >> 4) * 8;
#pragma unroll
                for (int m = 0; m < 4; ++m)
                    aF[m] = *(const s16x8*)&As[(wr * 64 + m * 16 + (lane & 15)) * BKP + kk];
#pragma unroll
                for (int n = 0; n < 4; ++n)
                    bF[n] = *(const s16x8*)&Bs[(wc * 64 + n * 16 + (lane & 15)) * BKP + kk];
#pragma unroll
                for (int m = 0; m < 4; ++m)
#pragma unroll
                    for (int n = 0; n < 4; ++n)
                        acc[m][n] = __builtin_amdgcn_mfma_f32_16x16x32_bf16(aF[m], bF[n], acc[m][n], 0, 0, 0);
            }
        }
        ushort_t* xp = xwb + (size_t)p * N_NODES * OUT_F;
        const float* rp = rsout + (size_t)p * N_NODES;
#pragma unroll
        for (int m = 0; m < 4; ++m) {
#pragma unroll
            for (int i = 0; i < 4; ++i) {
                int row = m0 + wr * 64 + m * 16 + (lane >> 4) * 4 + i;
                if (row < N_NODES) {
                    float rs = rp[row];
#pragma unroll
                    for (int n = 0; n < 4; ++n) {
                        int col = wc * 64 + n * 16 + (lane & 15);
                        xp[(size_t)row * OUT_F + col] = f2bf(acc[m][n][i] * rs);
                    }
                }
            }
        }
    }
}

// ---------------- scatter packed edges (src | dloc<<16) into bucket order, all paths ----------------
__global__ __launch_bounds__(256) void bscatter_kernel(const int* __restrict__ src,
                                                       const int* __restrict__ dst,
                                                       int* __restrict__ bcursor,
                                                       uint_t* __restrict__ ebuf)
{
    __shared__ uint_t bh[NBUCK];
    __shared__ uint_t lbase[NBUCK];
    int p = blockIdx.y;
    int t = threadIdx.x;
    int poff = p * E_EDGES;
    int* bcursor_p = bcursor + p * NBUCK;
    uint_t* ebuf_p = ebuf + (size_t)p * E_EDGES;
    for (int i = t; i < NBUCK; i += 256) bh[i] = 0;
    __syncthreads();
    size_t ebase = (size_t)p * E_EDGES + (size_t)blockIdx.x * CHUNK_E;
    const int4* d4 = (const int4*)(dst + ebase);
    const int4* s4 = (const int4*)(src + ebase);
    for (int i = t; i < CHUNK_E / 4; i += 256) {
        int4 v = d4[i];
        atomicAdd(&bh[v.x >> 7], 1u);
        atomicAdd(&bh[v.y >> 7], 1u);
        atomicAdd(&bh[v.z >> 7], 1u);
        atomicAdd(&bh[v.w >> 7], 1u);
    }
    __syncthreads();
    for (int i = t; i < NBUCK; i += 256) {
        uint_t c = bh[i];
        lbase[i] = c ? (uint_t)(atomicAdd(&bcursor_p[i], (int)c) - poff) : 0u;
        bh[i] = 0;     // reuse as local cursor
    }
    __syncthreads();
    for (int i = t; i < CHUNK_E / 4; i += 256) {
        int4 d = d4[i];
        int4 s = s4[i];
        { int bk = d.x >> 7; uint_t pos = lbase[bk] + atomicAdd(&bh[bk], 1u); ebuf_p[pos] = (uint_t)s.x | ((uint_t)(d.x & 127) << 16); }
        { int bk = d.y >> 7; uint_t pos = lbase[bk] + atomicAdd(&bh[bk], 1u); ebuf_p[pos] = (uint_t)s.y | ((uint_t)(d.y & 127) << 16); }
        { int bk = d.z >> 7; uint_t pos = lbase[bk] + atomicAdd(&bh[bk], 1u); ebuf_p[pos] = (uint_t)s.z | ((uint_t)(d.z & 127) << 16); }
        { int bk = d.w >> 7; uint_t pos = lbase[bk] + atomicAdd(&bh[bk], 1u); ebuf_p[pos] = (uint_t)s.w | ((uint_t)(d.w & 127) << 16); }
    }
}

// ---------------- FUSED: per-bucket local CSR build + gather (same-block dependency) ----------------
__global__ __launch_bounds__(256) void blocal_gather_kernel(const uint_t* __restrict__ ebuf,
                                                            const int* __restrict__ bstart,
                                                            ushort_t* __restrict__ eidx2,
                                                            const ushort_t* __restrict__ xwb,
                                                            const float* __restrict__ bconv,
                                                            uint4* __restrict__ hb)
{
    __shared__ uint_t hist[NPB];
    __shared__ uint_t cur[NPB];
    __shared__ uint_t nstart[NPB];
    __shared__ uint_t sa[NPB], sb[NPB];
    int bkt = blockIdx.x;
    int p = blockIdx.y;
    int t = threadIdx.x;
    int poff = p * E_EDGES;
    const uint_t* ebuf_p = ebuf + (size_t)p * E_EDGES;
    ushort_t* eidx2_p = eidx2 + (size_t)p * E_EDGES;
    if (t < NPB) hist[t] = 0;
    __syncthreads();
    int r0 = bstart[p * NBUCK + bkt] - poff;
    int r1 = bstart[p * NBUCK + bkt + 1] - poff;
    for (int e = r0 + t; e < r1; e += 256)
        atomicAdd(&hist[ebuf_p[e] >> 16], 1u);
    __syncthreads();
    if (t < NPB) sa[t] = hist[t];
    __syncthreads();
    uint_t* pin = sa; uint_t* pout = sb;
    for (int off = 1; off < NPB; off <<= 1) {
        if (t < NPB) pout[t] = pin[t] + (t >= off ? pin[t - off] : 0u);
        __syncthreads();
        uint_t* tmp = pin; pin = pout; pout = tmp;
    }
    if (t < NPB) {
        uint_t ex = pin[t] - hist[t];
        nstart[t] = ex;
        cur[t] = ex;
    }
    __syncthreads();
    for (int e = r0 + t; e < r1; e += 256) {
        uint_t pk = ebuf_p[e];
        int dl = (int)(pk >> 16);
        uint_t pos = atomicAdd(&cur[dl], 1u);
        eidx2_p[r0 + pos] = (ushort_t)(pk & 0xFFFFu);
    }
    __syncthreads();   // eidx2 writes visible block-wide; hist/nstart stable

    // ---- gather phase: half-wave per node, 16 nodes per half-wave, L2-hot eidx2 ----
    int hw = t >> 5, lane = t & 31;
    int sub = lane >> 4;                // which edge of the pair
    int c16 = lane & 15;                // col group: cols 8*c16 .. 8*c16+7
    const uint4* base = (const uint4*)xwb + (size_t)p * N_NODES * 16 + c16;
    float4 bc0 = *(const float4*)(bconv + (size_t)p * OUT_F + c16 * 8);
    float4 bc1 = *(const float4*)(bconv + (size_t)p * OUT_F + c16 * 8 + 4);
    for (int nl = hw * 16; nl < hw * 16 + 16; ++nl) {
        int node = bkt * NPB + nl;
        if (node >= N_NODES) break;
        int b = r0 + (int)nstart[nl];
        int e = b + (int)hist[nl];
        float4 a0 = make_float4(0.f, 0.f, 0.f, 0.f);
        float4 a1 = make_float4(0.f, 0.f, 0.f, 0.f);
        int i = b;
        for (; i + 8 <= e; i += 8) {    // 8 edges per iter (4 per sub-stream)
            int s0 = eidx2_p[i + sub];
            int s1 = eidx2_p[i + 2 + sub];
            int s2 = eidx2_p[i + 4 + sub];
            int s3 = eidx2_p[i + 6 + sub];
            uint4 w0 = base[(size_t)s0 * 16];
            uint4 w1 = base[(size_t)s1 * 16];
            uint4 w2 = base[(size_t)s2 * 16];
            uint4 w3 = base[(size_t)s3 * 16];
            acc8(a0, a1, w0); acc8(a0, a1, w1); acc8(a0, a1, w2); acc8(a0, a1, w3);
        }
        for (; i + 2 <= e; i += 2) {
            uint4 w = base[(size_t)eidx2_p[i + sub] * 16];
            acc8(a0, a1, w);
        }
        if (i < e && sub == 0) {        // odd last edge: lo sub-stream only
            uint4 w = base[(size_t)eidx2_p[i] * 16];
            acc8(a0, a1, w);
        }
        // merge the two edge sub-streams (lanes l <-> l^16 hold same cols)
        a0.x += __shfl_xor(a0.x, 16); a0.y += __shfl_xor(a0.y, 16);
        a0.z += __shfl_xor(a0.z, 16); a0.w += __shfl_xor(a0.w, 16);
        a1.x += __shfl_xor(a1.x, 16); a1.y += __shfl_xor(a1.y, 16);
        a1.z += __shfl_xor(a1.z, 16); a1.w += __shfl_xor(a1.w, 16);
        if (sub == 0) {
            int d = e - b;
            float sc = rsqrtf((float)(d > 0 ? d : 1));
            uint4 o;
            o.x = (uint_t)f2bf(fmaf(a0.x, sc, bc0.x)) | ((uint_t)f2bf(fmaf(a0.y, sc, bc0.y)) << 16);
            o.y = (uint_t)f2bf(fmaf(a0.z, sc, bc0.z)) | ((uint_t)f2bf(fmaf(a0.w, sc, bc0.w)) << 16);
            o.z = (uint_t)f2bf(fmaf(a1.x, sc, bc1.x)) | ((uint_t)f2bf(fmaf(a1.y, sc, bc1.y)) << 16);
            o.w = (uint_t)f2bf(fmaf(a1.z, sc, bc1.z)) | ((uint_t)f2bf(fmaf(a1.w, sc, bc1.w)) << 16);
            hb[((size_t)p * N_NODES + node) * 16 + c16] = o;
        }
    }
}

// ---------------- MFMA fc: ALL paths per block; Bs(fcw) staged once ----------------
__global__ __launch_bounds__(256) void fc_mfma_kernel(const ushort_t* __restrict__ hb,
                                                      const ushort_t* __restrict__ fcwb,
                                                      const float* __restrict__ fcb,
                                                      float* __restrict__ partial)
{
    __shared__ ushort_t As[128 * FP];   // 34 KB
    __shared__ ushort_t Bs[128 * FP];   // 34 KB
    __shared__ float red[2][128];
    int m0 = blockIdx.x * 128;
    int t = threadIdx.x;
    int wid = t >> 6, lane = t & 63;
    int wr = wid >> 1, wc = wid & 1;
    int srow = t >> 1, half = (t & 1) * 16;
    int gr = m0 + srow;
    {   // stage Bs once (fcw[o][k] row-major = [n][k])
#pragma unroll
        for (int c = 0; c < 4; ++c) {
            int kb = c * 32 + half;
            const ushort_t* bp = fcwb + (size_t)srow * OUT_F + kb;
            *(uint4*)&Bs[srow * FP + kb]     = *(const uint4*)(bp);
            *(uint4*)&Bs[srow * FP + kb + 8] = *(const uint4*)(bp + 8);
        }
    }
    for (int p = 0; p < P_PATHS; ++p) {
        __syncthreads();   // prev path reads of As / red done (also covers Bs staging)
        const ushort_t* hp = hb + (size_t)p * N_NODES * OUT_F;
#pragma unroll
        for (int c = 0; c < 4; ++c) {
            int kb = c * 32 + half;
            uint4 w0 = make_uint4(0, 0, 0, 0), w1 = w0;
            if (gr < N_NODES) {
                const ushort_t* ap = hp + (size_t)gr * OUT_F + kb;
                w0 = *(const uint4*)(ap);
                w1 = *(const uint4*)(ap + 8);
            }
            *(uint4*)&As[srow * FP + kb]     = w0;
            *(uint4*)&As[srow * FP + kb + 8] = w1;
        }
        __syncthreads();
        f32x4 acc[4][4] = {};
#pragma unroll
        for (int k0 = 0; k0 < OUT_F; k0 += 32) {
            s16x8 aF[4], bF[4];
            int kk = k0 + (lane >> 4) * 8;
#pragma unroll
            for (int m = 0; m < 4; ++m)
                aF[m] = *(const s16x8*)&As[(wr * 64 + m * 16 + (lane & 15)) * FP + kk];
#pragma unroll
            for (int n = 0; n < 4; ++n)
                bF[n] = *(const s16x8*)&Bs[(wc * 64 + n * 16 + (lane & 15)) * FP + kk];
#pragma unroll
            for (int m = 0; m < 4; ++m)
#pragma unroll
                for (int n = 0; n < 4; ++n)
                    acc[m][n] = __builtin_amdgcn_mfma_f32_16x16x32_bf16(aF[m], bF[n], acc[m][n], 0, 0, 0);
        }
#pragma unroll
        for (int n = 0; n < 4; ++n) {
            int col = wc * 64 + n * 16 + (lane & 15);
            float fb = fcb[col];
            float s = 0.f;
#pragma unroll
            for (int m = 0; m < 4; ++m)
#pragma unroll
                for (int i = 0; i < 4; ++i) {
                    int row = m0 + wr * 64 + m * 16 + (lane >> 4) * 4 + i;
                    if (row < N_NODES) s += fast_tanh(acc[m][n][i] + fb);
                }
            s += __shfl_xor(s, 16);
            s += __shfl_xor(s, 32);
            if (lane < 16) red[wr][col] = s;
        }
        __syncthreads();
        if (t < 128)
            partial[((size_t)p * GBLK + blockIdx.x) * OUT_F + t] = red[0][t] + red[1][t];
    }
}

// ---------------- reduce partials -> sp -> beta softmax (1024 threads) ----------------
__global__ __launch_bounds__(1024) void beta_reduce_kernel(const float* __restrict__ partial,
                                                           const float* __restrict__ att,
                                                           float* __restrict__ beta)
{
    int t = threadIdx.x;           // 1024 = P*128*2
    int p = t >> 8;                // path
    int r = t & 255;
    int c = r & 127;               // column
    int hf = r >> 7;               // half of GBLK rows
    float s = 0.f;
    for (int i = hf; i < GBLK; i += 2)
        s += partial[((size_t)p * GBLK + i) * OUT_F + c];
    __shared__ float red[1024];
    red[t] = s;
    __syncthreads();
    if (hf == 0)
        red[t] = (red[t] + red[t + 128]) * att[p * OUT_F + c] * (1.0f / N_NODES);
    __syncthreads();
    for (int off = 64; off >= 1; off >>= 1) {
        if (hf == 0 && c < off) red[t] += red[t + off];
        __syncthreads();
    }
    if (t == 0) {
        float w[P_PATHS], mx = -1e30f;
        for (int q = 0; q < P_PATHS; ++q) { w[q] = red[q * 256]; mx = fmaxf(mx, w[q]); }
        float sum = 0.f;
        for (int q = 0; q < P_PATHS; ++q) { w[q] = expf(w[q] - mx); sum += w[q]; }
        for (int q = 0; q < P_PATHS; ++q) beta[q] = w[q] / sum;
    }
}

// ---------------- out = sum_p beta[p]*h[p] + h_bias ----------------
__global__ void combine_kernel(const uint_t* __restrict__ hb, const float* __restrict__ hbias,
                               const float* __restrict__ beta, float* __restrict__ out)
{
    int idx = blockIdx.x * blockDim.x + threadIdx.x;   // over N*64
    if (idx >= N_NODES * 64) return;
    int n = idx >> 6;
    int w = idx & 63;
    float2 hbv = *(const float2*)(hbias + 2 * w);
    float r0 = hbv.x, r1 = hbv.y;
#pragma unroll
    for (int p = 0; p < P_PATHS; ++p) {
        float bp = beta[p];
        uint_t v = hb[((size_t)p * N_NODES + n) * 64 + w];
        r0 = fmaf(bp, bf2f((ushort_t)v), r0);
        r1 = fmaf(bp, bf2f((ushort_t)(v >> 16)), r1);
    }
    *(float2*)(out + (size_t)n * OUT_F + 2 * w) = make_float2(r0, r1);
}

extern "C" void kernel_launch(void* const* d_in, const int* in_sizes, int n_in,
                              void* d_out, int out_size, void* d_ws, size_t ws_size,
                              hipStream_t stream)
{
    const float* x      = (const float*)d_in[0];
    const float* W      = (const float*)d_in[1];
    const float* b_conv = (const float*)d_in[2];
    const float* att    = (const float*)d_in[3];
    const float* fc_w   = (const float*)d_in[4];
    const float* fc_b   = (const float*)d_in[5];
    const float* h_bias = (const float*)d_in[6];
    const int*   src    = (const int*)d_in[7];
    const int*   dst    = (const int*)d_in[8];
    float* out = (float*)d_out;
    float* ws  = (float*)d_ws;

    // ---- ws layout, total ~132.3 MB ----
    size_t off_rsout   = 0;                                            // P*N f32
    size_t off_partial = off_rsout + (size_t)P_PATHS * N_NODES;        // P*GBLK*128 f32
    size_t off_beta    = off_partial + (size_t)P_PATHS * GBLK * OUT_F;
    size_t off_i32     = (off_beta + 4 + 63) & ~(size_t)63;
    // int region (units of int)
    size_t i_bstart  = 0;                                  // P*NBUCK+1 -> pad 1600
    size_t i_bcursor = 1600;                               // P*NBUCK
    size_t i_bcounts = 3200;                               // P*NBUCK
    size_t i_dhist   = 4800;                               // P*QTR*DSL*Q_W = 2,000,000
    size_t i_ebuf    = i_dhist + (size_t)P_PATHS * QTR * DSL * Q_W;   // P*E
    size_t n_ints    = i_ebuf + (size_t)P_PATHS * E_EDGES;
    size_t off_u16   = off_i32 + ((n_ints + 63) & ~(size_t)63);
    // ushort region (units of ushort)
    size_t u_hb    = 0;                                    // P*N*128
    size_t u_xwb   = u_hb + (size_t)P_PATHS * N_NODES * OUT_F;   // P*N*128
    size_t u_eidx2 = u_xwb + (size_t)P_PATHS * N_NODES * OUT_F;  // P*E
    size_t u_Wt    = u_eidx2 + (size_t)P_PATHS * E_EDGES;        // P*IN*OUT
    size_t u_fcwb  = u_Wt + (size_t)P_PATHS * IN_F * OUT_F;      // OUT*OUT

    float* rsout   = ws + off_rsout;
    float* partial = ws + off_partial;
    float* beta    = ws + off_beta;
    int*   ibase   = (int*)(ws + off_i32);
    int*    bstart  = ibase + i_bstart;
    int*    bcursor = ibase + i_bcursor;
    uint_t* bcounts = (uint_t*)(ibase + i_bcounts);
    uint_t* dhist   = (uint_t*)(ibase + i_dhist);
    uint_t* ebuf    = (uint_t*)(ibase + i_ebuf);
    ushort_t* ubase = (ushort_t*)(ws + off_u16);
    ushort_t* hb    = ubase + u_hb;
    ushort_t* xwb   = ubase + u_xwb;
    ushort_t* eidx2 = ubase + u_eidx2;
    ushort_t* Wt    = ubase + u_Wt;
    ushort_t* fcwb  = ubase + u_fcwb;

    // only bucket counters accumulate -> zero each call
    hipMemsetAsync(bcounts, 0, (size_t)P_PATHS * NBUCK * sizeof(uint_t), stream);

    deghist_kernel<<<dim3(DSL, QTR + 2, P_PATHS), 256, 0, stream>>>(
        src, dst, dhist, bcounts, W, fc_w, Wt, fcwb);
    rsout_bscan_kernel<<<RSB + 1, 1024, 0, stream>>>(dhist, rsout, bcounts, bstart, bcursor);

    gemm_xall_kernel<<<dim3(GBLK, 2), 256, 0, stream>>>(x, Wt, rsout, xwb);
    bscatter_kernel<<<dim3(NCHUNK, P_PATHS), 256, 0, stream>>>(src, dst, bcursor, ebuf);
    blocal_gather_kernel<<<dim3(NBUCK, P_PATHS), 256, 0, stream>>>(
        ebuf, bstart, eidx2, xwb, b_conv, (uint4*)hb);
    fc_mfma_kernel<<<GBLK, 256, 0, stream>>>(hb, fcwb, fc_b, partial);

    beta_reduce_kernel<<<1, 1024, 0, stream>>>(partial, att, beta);
    combine_kernel<<<(N_NODES * 64 + 255) / 256, 256, 0, stream>>>(
        (const uint_t*)hb, h_bias, beta, out);
}

// Round 12
// 351.762 us; speedup vs baseline: 1.0713x; 1.0713x over previous
//
#include <hip/hip_runtime.h>
#include <math.h>

#define N_NODES 50000
#define P_PATHS 4
#define E_EDGES 800000
#define IN_F 256
#define OUT_F 128
#define NPB 128                        // nodes per bucket
#define NBUCK 391                      // ceil(N/NPB)
#define NCHUNK 200                     // edge chunks per path
#define CHUNK_E (E_EDGES / NCHUNK)     // 4000
#define GBLK 391                       // row-blocks for gemm/fc (128 rows each)
#define DSL 20                         // edge slices for deg-out histogram
#define FW 12500                       // full-range words, 4×u8 packed (50KB LDS)
#define BKP 72                         // LDS pitch (u16) for BK=64 gemm tiles
#define FP 136                         // LDS pitch (u16) for K=128 tiles
#define RSB 49                         // rsout blocks (ceil(P*FW/1024)) in merged rsout+bscan

typedef unsigned short ushort_t;
typedef unsigned int uint_t;
typedef float f32x4 __attribute__((ext_vector_type(4)));
typedef short s16x8 __attribute__((ext_vector_type(8)));

__device__ __forceinline__ ushort_t f2bf(float f) {
    uint_t u = __float_as_uint(f);
    return (ushort_t)((u + 0x7FFFu + ((u >> 16) & 1u)) >> 16);   // RNE
}
__device__ __forceinline__ float bf2f(ushort_t h) {
    return __uint_as_float(((uint_t)h) << 16);
}
__device__ __forceinline__ uint4 pack8(const float4 f0, const float4 f1) {
    uint4 w;
    w.x = (uint_t)f2bf(f0.x) | ((uint_t)f2bf(f0.y) << 16);
    w.y = (uint_t)f2bf(f0.z) | ((uint_t)f2bf(f0.w) << 16);
    w.z = (uint_t)f2bf(f1.x) | ((uint_t)f2bf(f1.y) << 16);
    w.w = (uint_t)f2bf(f1.z) | ((uint_t)f2bf(f1.w) << 16);
    return w;
}
__device__ __forceinline__ float fast_tanh(float v) {
    v = fminf(fmaxf(v, -20.f), 20.f);
    float ex = __expf(2.f * v);
    return (ex - 1.f) / (ex + 1.f);
}
__device__ __forceinline__ void acc8(float4& a0, float4& a1, uint4 w) {
    a0.x += bf2f((ushort_t)w.x);  a0.y += bf2f((ushort_t)(w.x >> 16));
    a0.z += bf2f((ushort_t)w.y);  a0.w += bf2f((ushort_t)(w.y >> 16));
    a1.x += bf2f((ushort_t)w.z);  a1.y += bf2f((ushort_t)(w.z >> 16));
    a1.z += bf2f((ushort_t)w.w);  a1.w += bf2f((ushort_t)(w.w >> 16));
}

// -------- deg_out full-range u8 hist (q==0) + dst bucket hist (q==1) + prep (q==2) --------
__global__ __launch_bounds__(256) void deghist_kernel(const int* __restrict__ src,
                                                      const int* __restrict__ dst,
                                                      uint_t* __restrict__ dhist,
                                                      uint_t* __restrict__ bcounts,
                                                      const float* __restrict__ W,
                                                      const float* __restrict__ fcw,
                                                      ushort_t* __restrict__ Wt,
                                                      ushort_t* __restrict__ fcwb)
{
    __shared__ uint_t cnt[FW];   // 50 KB
    int sl = blockIdx.x, q = blockIdx.y, p = blockIdx.z;
    int t = threadIdx.x;
    if (q == 2) {
        // prep: W -> Wt bf16 transposed, fc_w -> bf16 (80 blocks total)
        int g = (p * DSL + sl) * 256 + t;
        for (int idx = g; idx < P_PATHS * IN_F * OUT_F; idx += DSL * P_PATHS * 256) {
            int pp = idx >> 15;
            int r = idx & 32767;
            int k = r >> 7;
            int n = r & 127;
            Wt[((size_t)pp << 15) + (size_t)n * IN_F + k] = f2bf(W[idx]);
        }
        for (int idx = g; idx < OUT_F * OUT_F; idx += DSL * P_PATHS * 256)
            fcwb[idx] = f2bf(fcw[idx]);
        return;
    }
    if (q == 1) {
        // bucket histogram (by dst>>7) for this slice
        for (int i = t; i < NBUCK; i += 256) cnt[i] = 0;
        __syncthreads();
        const int4* d4 = (const int4*)(dst + (size_t)p * E_EDGES + (size_t)sl * (E_EDGES / DSL));
        for (int i = t; i < E_EDGES / DSL / 4; i += 256) {
            int4 v = d4[i];
            atomicAdd(&cnt[v.x >> 7], 1u);
            atomicAdd(&cnt[v.y >> 7], 1u);
            atomicAdd(&cnt[v.z >> 7], 1u);
            atomicAdd(&cnt[v.w >> 7], 1u);
        }
        __syncthreads();
        for (int i = t; i < NBUCK; i += 256)
            if (cnt[i]) atomicAdd(&bcounts[p * NBUCK + i], cnt[i]);
        return;
    }
    // q == 0: full-range src histogram, u8-packed (per-slice counts << 255)
    for (int i = t; i < FW; i += 256) cnt[i] = 0;
    __syncthreads();
    const int4* s4 = (const int4*)(src + (size_t)p * E_EDGES + (size_t)sl * (E_EDGES / DSL));
    for (int i = t; i < E_EDGES / DSL / 4; i += 256) {
        int4 v = s4[i];
        atomicAdd(&cnt[(uint_t)v.x >> 2], 1u << (((uint_t)v.x & 3u) * 8));
        atomicAdd(&cnt[(uint_t)v.y >> 2], 1u << (((uint_t)v.y & 3u) * 8));
        atomicAdd(&cnt[(uint_t)v.z >> 2], 1u << (((uint_t)v.z & 3u) * 8));
        atomicAdd(&cnt[(uint_t)v.w >> 2], 1u << (((uint_t)v.w & 3u) * 8));
    }
    __syncthreads();
    uint_t* outp = dhist + ((size_t)p * DSL + sl) * FW;
    for (int i = t; i < FW; i += 256) outp[i] = cnt[i];
}

// ---------------- merged: blocks 0..RSB-1 -> rsout; block RSB -> bucket scan ----------------
__global__ __launch_bounds__(1024) void rsout_bscan_kernel(const uint_t* __restrict__ dhist,
                                                           float* __restrict__ rsout,
                                                           const uint_t* __restrict__ bcounts,
                                                           int* __restrict__ bstart,
                                                           int* __restrict__ bcursor)
{
    int t = threadIdx.x;
    if (blockIdx.x == RSB) {
        __shared__ int a[2048], b[2048];
        for (int i = t; i < 2048; i += 1024)
            a[i] = (i < P_PATHS * NBUCK) ? (int)bcounts[i] : 0;
        __syncthreads();
        int* pin = a; int* pout = b;
        for (int off = 1; off < 2048; off <<= 1) {
            for (int i = t; i < 2048; i += 1024)
                pout[i] = pin[i] + (i >= off ? pin[i - off] : 0);
            __syncthreads();
            int* tmp = pin; pin = pout; pout = tmp;
        }
        for (int i = t; i < P_PATHS * NBUCK; i += 1024) {
            int st = pin[i] - (int)bcounts[i];
            bstart[i] = st;
            bcursor[i] = st;
        }
        if (t == 0) bstart[P_PATHS * NBUCK] = pin[P_PATHS * NBUCK - 1];
        return;
    }
    int idx = blockIdx.x * 1024 + t;      // over P*FW
    if (idx >= P_PATHS * FW) return;
    int p = idx / FW;
    int w = idx % FW;
    const uint_t* base = dhist + (size_t)p * DSL * FW + w;
    uint_t s = 0;
#pragma unroll
    for (int sl = 0; sl < DSL; ++sl) s += base[(size_t)sl * FW];
    int node = 4 * w;
    float* rp = rsout + (size_t)p * N_NODES + node;
    uint_t c0 = s & 0xFFu, c1 = (s >> 8) & 0xFFu, c2 = (s >> 16) & 0xFFu, c3 = s >> 24;
    rp[0] = rsqrtf((float)(c0 ? c0 : 1u));
    rp[1] = rsqrtf((float)(c1 ? c1 : 1u));
    rp[2] = rsqrtf((float)(c2 ? c2 : 1u));
    rp[3] = rsqrtf((float)(c3 ? c3 : 1u));
}

// ---------------- MFMA GEMM, BK=64 tiles, path-pair per block ----------------
__global__ __launch_bounds__(256) void gemm_xall_kernel(const float* __restrict__ x,
                                                        const ushort_t* __restrict__ Wt,
                                                        const float* __restrict__ rsout,
                                                        ushort_t* __restrict__ xwb)
{
    __shared__ ushort_t As[128 * BKP];   // 18.4 KB
    __shared__ ushort_t Bs[128 * BKP];   // 18.4 KB
    int m0 = blockIdx.x * 128;
    int t = threadIdx.x;
    int wid = t >> 6, lane = t & 63;
    int wr = wid >> 1, wc = wid & 1;
    int srow = t >> 1, h32 = (t & 1) * 32;
    int gr = m0 + srow;
    for (int pp = 0; pp < 2; ++pp) {
        int p = blockIdx.y * 2 + pp;
        const ushort_t* Wp = Wt + ((size_t)p << 15);
        f32x4 acc[4][4] = {};
        for (int kt = 0; kt < 4; ++kt) {
            __syncthreads();   // prior tile reads done
            {   // A: 128x64 fp32 -> bf16
                const float* ap = x + (size_t)gr * IN_F + kt * 64 + h32;
#pragma unroll
                for (int c = 0; c < 4; ++c) {
                    float4 f0 = make_float4(0.f, 0.f, 0.f, 0.f), f1 = f0;
                    if (gr < N_NODES) {
                        f0 = *(const float4*)(ap + c * 8);
                        f1 = *(const float4*)(ap + c * 8 + 4);
                    }
                    *(uint4*)&As[srow * BKP + h32 + c * 8] = pack8(f0, f1);
                }
            }
            {   // B: Wt rows direct u16 copy
                const ushort_t* bp = Wp + (size_t)srow * IN_F + kt * 64 + h32;
#pragma unroll
                for (int c = 0; c < 4; ++c)
                    *(uint4*)&Bs[srow * BKP + h32 + c * 8] = *(const uint4*)(bp + c * 8);
            }
            __syncthreads();
#pragma unroll
            for (int k0 = 0; k0 < 64; k0 += 32) {
                s16x8 aF[4], bF[4];
                int kk = k0 + (lane >> 4) * 8;
#pragma unroll
                for (int m = 0; m < 4; ++m)
                    aF[m] = *(const s16x8*)&As[(wr * 64 + m * 16 + (lane & 15)) * BKP + kk];
#pragma unroll
                for (int n = 0; n < 4; ++n)
                    bF[n] = *(const s16x8*)&Bs[(wc * 64 + n * 16 + (lane & 15)) * BKP + kk];
#pragma unroll
                for (int m = 0; m < 4; ++m)
#pragma unroll
                    for (int n = 0; n < 4; ++n)
                        acc[m][n] = __builtin_amdgcn_mfma_f32_16x16x32_bf16(aF[m], bF[n], acc[m][n], 0, 0, 0);
            }
        }
        ushort_t* xp = xwb + (size_t)p * N_NODES * OUT_F;
        const float* rp = rsout + (size_t)p * N_NODES;
#pragma unroll
        for (int m = 0; m < 4; ++m) {
#pragma unroll
            for (int i = 0; i < 4; ++i) {
                int row = m0 + wr * 64 + m * 16 + (lane >> 4) * 4 + i;
                if (row < N_NODES) {
                    float rs = rp[row];
#pragma unroll
                    for (int n = 0; n < 4; ++n) {
                        int col = wc * 64 + n * 16 + (lane & 15);
                        xp[(size_t)row * OUT_F + col] = f2bf(acc[m][n][i] * rs);
                    }
                }
            }
        }
    }
}

// ---------------- scatter packed edges (src | dloc<<16) into bucket order, all paths ----------------
__global__ __launch_bounds__(256) void bscatter_kernel(const int* __restrict__ src,
                                                       const int* __restrict__ dst,
                                                       int* __restrict__ bcursor,
                                                       uint_t* __restrict__ ebuf)
{
    __shared__ uint_t bh[NBUCK];
    __shared__ uint_t lbase[NBUCK];
    int p = blockIdx.y;
    int t = threadIdx.x;
    int poff = p * E_EDGES;
    int* bcursor_p = bcursor + p * NBUCK;
    uint_t* ebuf_p = ebuf + (size_t)p * E_EDGES;
    for (int i = t; i < NBUCK; i += 256) bh[i] = 0;
    __syncthreads();
    size_t ebase = (size_t)p * E_EDGES + (size_t)blockIdx.x * CHUNK_E;
    const int4* d4 = (const int4*)(dst + ebase);
    const int4* s4 = (const int4*)(src + ebase);
    for (int i = t; i < CHUNK_E / 4; i += 256) {
        int4 v = d4[i];
        atomicAdd(&bh[v.x >> 7], 1u);
        atomicAdd(&bh[v.y >> 7], 1u);
        atomicAdd(&bh[v.z >> 7], 1u);
        atomicAdd(&bh[v.w >> 7], 1u);
    }
    __syncthreads();
    for (int i = t; i < NBUCK; i += 256) {
        uint_t c = bh[i];
        lbase[i] = c ? (uint_t)(atomicAdd(&bcursor_p[i], (int)c) - poff) : 0u;
        bh[i] = 0;     // reuse as local cursor
    }
    __syncthreads();
    for (int i = t; i < CHUNK_E / 4; i += 256) {
        int4 d = d4[i];
        int4 s = s4[i];
        { int bk = d.x >> 7; uint_t pos = lbase[bk] + atomicAdd(&bh[bk], 1u); ebuf_p[pos] = (uint_t)s.x | ((uint_t)(d.x & 127) << 16); }
        { int bk = d.y >> 7; uint_t pos = lbase[bk] + atomicAdd(&bh[bk], 1u); ebuf_p[pos] = (uint_t)s.y | ((uint_t)(d.y & 127) << 16); }
        { int bk = d.z >> 7; uint_t pos = lbase[bk] + atomicAdd(&bh[bk], 1u); ebuf_p[pos] = (uint_t)s.z | ((uint_t)(d.z & 127) << 16); }
        { int bk = d.w >> 7; uint_t pos = lbase[bk] + atomicAdd(&bh[bk], 1u); ebuf_p[pos] = (uint_t)s.w | ((uint_t)(d.w & 127) << 16); }
    }
}

// ---------------- per-bucket local CSR build, all paths ----------------
__global__ __launch_bounds__(256) void blocal_kernel(const uint_t* __restrict__ ebuf,
                                                     const int* __restrict__ bstart,
                                                     ushort_t* __restrict__ eidx2,
                                                     int* __restrict__ rsn)
{
    __shared__ uint_t hist[NPB];
    __shared__ uint_t cur[NPB];
    __shared__ uint_t sa[NPB], sb[NPB];
    int bkt = blockIdx.x;
    int p = blockIdx.y;
    int t = threadIdx.x;
    int poff = p * E_EDGES;
    const uint_t* ebuf_p = ebuf + (size_t)p * E_EDGES;
    ushort_t* eidx2_p = eidx2 + (size_t)p * E_EDGES;
    int* rsn_p = rsn + (size_t)p * (N_NODES + 1);
    if (t < NPB) hist[t] = 0;
    __syncthreads();
    int r0 = bstart[p * NBUCK + bkt] - poff;
    int r1 = bstart[p * NBUCK + bkt + 1] - poff;
    for (int e = r0 + t; e < r1; e += 256)
        atomicAdd(&hist[ebuf_p[e] >> 16], 1u);
    __syncthreads();
    if (t < NPB) sa[t] = hist[t];
    __syncthreads();
    uint_t* pin = sa; uint_t* pout = sb;
    for (int off = 1; off < NPB; off <<= 1) {
        if (t < NPB) pout[t] = pin[t] + (t >= off ? pin[t - off] : 0u);
        __syncthreads();
        uint_t* tmp = pin; pin = pout; pout = tmp;
    }
    if (t < NPB) {
        uint_t ex = pin[t] - hist[t];
        int node = bkt * NPB + t;
        if (node < N_NODES) rsn_p[node] = r0 + (int)ex;
        cur[t] = ex;
    }
    if (bkt == NBUCK - 1 && t == 0) rsn_p[N_NODES] = r1;   // == E_EDGES
    __syncthreads();
    for (int e = r0 + t; e < r1; e += 256) {
        uint_t pk = ebuf_p[e];
        int dl = (int)(pk >> 16);
        uint_t pos = atomicAdd(&cur[dl], 1u);
        eidx2_p[r0 + pos] = (ushort_t)(pk & 0xFFFFu);
    }
}

// ---------------- gather v4: half-wave per node, 2 edges per uint4 load, shfl merge ----------------
__global__ __launch_bounds__(256) void gather_kernel(const ushort_t* __restrict__ xwb,
                                                     const ushort_t* __restrict__ eidx2,
                                                     const int* __restrict__ rsn,
                                                     const float* __restrict__ bconv,
                                                     uint4* __restrict__ hb)   // row = 16 uint4
{
    int hw = threadIdx.x >> 5;          // half-wave 0..7
    int lane = threadIdx.x & 31;
    int sub = lane >> 4;                // which edge of the pair
    int c16 = lane & 15;                // col group: cols 8*c16 .. 8*c16+7
    int p = blockIdx.y;
    int n = blockIdx.x * 8 + hw;
    const int* rsn_p = rsn + (size_t)p * (N_NODES + 1);
    const ushort_t* ei = eidx2 + (size_t)p * E_EDGES;
    int b = rsn_p[n], e = rsn_p[n + 1];
    const uint4* base = (const uint4*)xwb + (size_t)p * N_NODES * 16 + c16;
    float4 a0 = make_float4(0.f, 0.f, 0.f, 0.f);
    float4 a1 = make_float4(0.f, 0.f, 0.f, 0.f);
    int i = b;
    for (; i + 8 <= e; i += 8) {        // 8 edges per iter (4 per sub-stream)
        int s0 = ei[i + sub];
        int s1 = ei[i + 2 + sub];
        int s2 = ei[i + 4 + sub];
        int s3 = ei[i + 6 + sub];
        uint4 w0 = base[(size_t)s0 * 16];
        uint4 w1 = base[(size_t)s1 * 16];
        uint4 w2 = base[(size_t)s2 * 16];
        uint4 w3 = base[(size_t)s3 * 16];
        acc8(a0, a1, w0); acc8(a0, a1, w1); acc8(a0, a1, w2); acc8(a0, a1, w3);
    }
    for (; i + 2 <= e; i += 2) {
        int s = ei[i + sub];
        uint4 w = base[(size_t)s * 16];
        acc8(a0, a1, w);
    }
    if (i < e && sub == 0) {            // odd last edge: lo sub-stream only
        int s = ei[i];
        uint4 w = base[(size_t)s * 16];
        acc8(a0, a1, w);
    }
    // merge the two edge sub-streams (lanes l <-> l^16 hold same cols)
    a0.x += __shfl_xor(a0.x, 16); a0.y += __shfl_xor(a0.y, 16);
    a0.z += __shfl_xor(a0.z, 16); a0.w += __shfl_xor(a0.w, 16);
    a1.x += __shfl_xor(a1.x, 16); a1.y += __shfl_xor(a1.y, 16);
    a1.z += __shfl_xor(a1.z, 16); a1.w += __shfl_xor(a1.w, 16);
    if (sub == 0) {
        int d = e - b;
        float sc = rsqrtf((float)(d > 0 ? d : 1));
        float4 bc0 = *(const float4*)(bconv + (size_t)p * OUT_F + c16 * 8);
        float4 bc1 = *(const float4*)(bconv + (size_t)p * OUT_F + c16 * 8 + 4);
        uint4 o;
        o.x = (uint_t)f2bf(fmaf(a0.x, sc, bc0.x)) | ((uint_t)f2bf(fmaf(a0.y, sc, bc0.y)) << 16);
        o.y = (uint_t)f2bf(fmaf(a0.z, sc, bc0.z)) | ((uint_t)f2bf(fmaf(a0.w, sc, bc0.w)) << 16);
        o.z = (uint_t)f2bf(fmaf(a1.x, sc, bc1.x)) | ((uint_t)f2bf(fmaf(a1.y, sc, bc1.y)) << 16);
        o.w = (uint_t)f2bf(fmaf(a1.z, sc, bc1.z)) | ((uint_t)f2bf(fmaf(a1.w, sc, bc1.w)) << 16);
        hb[((size_t)p * N_NODES + n) * 16 + c16] = o;
    }
}

// ---------------- MFMA fc: ALL paths per block; Bs(fcw) staged once ----------------
__global__ __launch_bounds__(256) void fc_mfma_kernel(const ushort_t* __restrict__ hb,
                                                      const ushort_t* __restrict__ fcwb,
                                                      const float* __restrict__ fcb,
                                                      float* __restrict__ partial)
{
    __shared__ ushort_t As[128 * FP];   // 34 KB
    __shared__ ushort_t Bs[128 * FP];   // 34 KB
    __shared__ float red[2][128];
    int m0 = blockIdx.x * 128;
    int t = threadIdx.x;
    int wid = t >> 6, lane = t & 63;
    int wr = wid >> 1, wc = wid & 1;
    int srow = t >> 1, half = (t & 1) * 16;
    int gr = m0 + srow;
    {   // stage Bs once (fcw[o][k] row-major = [n][k])
#pragma unroll
        for (int c = 0; c < 4; ++c) {
            int kb = c * 32 + half;
            const ushort_t* bp = fcwb + (size_t)srow * OUT_F + kb;
            *(uint4*)&Bs[srow * FP + kb]     = *(const uint4*)(bp);
            *(uint4*)&Bs[srow * FP + kb + 8] = *(const uint4*)(bp + 8);
        }
    }
    for (int p = 0; p < P_PATHS; ++p) {
        __syncthreads();   // prev path reads of As / red done (also covers Bs staging)
        const ushort_t* hp = hb + (size_t)p * N_NODES * OUT_F;
#pragma unroll
        for (int c = 0; c < 4; ++c) {
            int kb = c * 32 + half;
            uint4 w0 = make_uint4(0, 0, 0, 0), w1 = w0;
            if (gr < N_NODES) {
                const ushort_t* ap = hp + (size_t)gr * OUT_F + kb;
                w0 = *(const uint4*)(ap);
                w1 = *(const uint4*)(ap + 8);
            }
            *(uint4*)&As[srow * FP + kb]     = w0;
            *(uint4*)&As[srow * FP + kb + 8] = w1;
        }
        __syncthreads();
        f32x4 acc[4][4] = {};
#pragma unroll
        for (int k0 = 0; k0 < OUT_F; k0 += 32) {
            s16x8 aF[4], bF[4];
            int kk = k0 + (lane >> 4) * 8;
#pragma unroll
            for (int m = 0; m < 4; ++m)
                aF[m] = *(const s16x8*)&As[(wr * 64 + m * 16 + (lane & 15)) * FP + kk];
#pragma unroll
            for (int n = 0; n < 4; ++n)
                bF[n] = *(const s16x8*)&Bs[(wc * 64 + n * 16 + (lane & 15)) * FP + kk];
#pragma unroll
            for (int m = 0; m < 4; ++m)
#pragma unroll
                for (int n = 0; n < 4; ++n)
                    acc[m][n] = __builtin_amdgcn_mfma_f32_16x16x32_bf16(aF[m], bF[n], acc[m][n], 0, 0, 0);
        }
#pragma unroll
        for (int n = 0; n < 4; ++n) {
            int col = wc * 64 + n * 16 + (lane & 15);
            float fb = fcb[col];
            float s = 0.f;
#pragma unroll
            for (int m = 0; m < 4; ++m)
#pragma unroll
                for (int i = 0; i < 4; ++i) {
                    int row = m0 + wr * 64 + m * 16 + (lane >> 4) * 4 + i;
                    if (row < N_NODES) s += fast_tanh(acc[m][n][i] + fb);
                }
            s += __shfl_xor(s, 16);
            s += __shfl_xor(s, 32);
            if (lane < 16) red[wr][col] = s;
        }
        __syncthreads();
        if (t < 128)
            partial[((size_t)p * GBLK + blockIdx.x) * OUT_F + t] = red[0][t] + red[1][t];
    }
}

// ---------------- reduce partials -> sp -> beta softmax (1024 threads) ----------------
__global__ __launch_bounds__(1024) void beta_reduce_kernel(const float* __restrict__ partial,
                                                           const float* __restrict__ att,
                                                           float* __restrict__ beta)
{
    int t = threadIdx.x;           // 1024 = P*128*2
    int p = t >> 8;                // path
    int r = t & 255;
    int c = r & 127;               // column
    int hf = r >> 7;               // half of GBLK rows
    float s = 0.f;
    for (int i = hf; i < GBLK; i += 2)
        s += partial[((size_t)p * GBLK + i) * OUT_F + c];
    __shared__ float red[1024];
    red[t] = s;
    __syncthreads();
    if (hf == 0)
        red[t] = (red[t] + red[t + 128]) * att[p * OUT_F + c] * (1.0f / N_NODES);
    __syncthreads();
    for (int off = 64; off >= 1; off >>= 1) {
        if (hf == 0 && c < off) red[t] += red[t + off];
        __syncthreads();
    }
    if (t == 0) {
        float w[P_PATHS], mx = -1e30f;
        for (int q = 0; q < P_PATHS; ++q) { w[q] = red[q * 256]; mx = fmaxf(mx, w[q]); }
        float sum = 0.f;
        for (int q = 0; q < P_PATHS; ++q) { w[q] = expf(w[q] - mx); sum += w[q]; }
        for (int q = 0; q < P_PATHS; ++q) beta[q] = w[q] / sum;
    }
}

// ---------------- out = sum_p beta[p]*h[p] + h_bias ----------------
__global__ void combine_kernel(const uint_t* __restrict__ hb, const float* __restrict__ hbias,
                               const float* __restrict__ beta, float* __restrict__ out)
{
    int idx = blockIdx.x * blockDim.x + threadIdx.x;   // over N*64
    if (idx >= N_NODES * 64) return;
    int n = idx >> 6;
    int w = idx & 63;
    float2 hbv = *(const float2*)(hbias + 2 * w);
    float r0 = hbv.x, r1 = hbv.y;
#pragma unroll
    for (int p = 0; p < P_PATHS; ++p) {
        float bp = beta[p];
        uint_t v = hb[((size_t)p * N_NODES + n) * 64 + w];
        r0 = fmaf(bp, bf2f((ushort_t)v), r0);
        r1 = fmaf(bp, bf2f((ushort_t)(v >> 16)), r1);
    }
    *(float2*)(out + (size_t)n * OUT_F + 2 * w) = make_float2(r0, r1);
}

extern "C" void kernel_launch(void* const* d_in, const int* in_sizes, int n_in,
                              void* d_out, int out_size, void* d_ws, size_t ws_size,
                              hipStream_t stream)
{
    const float* x      = (const float*)d_in[0];
    const float* W      = (const float*)d_in[1];
    const float* b_conv = (const float*)d_in[2];
    const float* att    = (const float*)d_in[3];
    const float* fc_w   = (const float*)d_in[4];
    const float* fc_b   = (const float*)d_in[5];
    const float* h_bias = (const float*)d_in[6];
    const int*   src    = (const int*)d_in[7];
    const int*   dst    = (const int*)d_in[8];
    float* out = (float*)d_out;
    float* ws  = (float*)d_ws;

    // ---- ws layout ----
    size_t off_rsout   = 0;                                            // P*N f32
    size_t off_partial = off_rsout + (size_t)P_PATHS * N_NODES;        // P*GBLK*128 f32
    size_t off_beta    = off_partial + (size_t)P_PATHS * GBLK * OUT_F;
    size_t off_i32     = (off_beta + 4 + 63) & ~(size_t)63;
    // int region (units of int)
    size_t i_bstart  = 0;                                  // P*NBUCK+1 -> pad 1600
    size_t i_bcursor = 1600;                               // P*NBUCK
    size_t i_bcounts = 3200;                               // P*NBUCK
    size_t i_rsn     = 4800;                               // P*(N+1) -> pad 204864
    size_t i_dhist   = 204864;                             // P*DSL*FW = 1,000,000
    size_t i_ebuf    = i_dhist + (size_t)P_PATHS * DSL * FW;          // P*E
    size_t n_ints    = i_ebuf + (size_t)P_PATHS * E_EDGES;
    size_t off_u16   = off_i32 + ((n_ints + 63) & ~(size_t)63);
    // ushort region (units of ushort)
    size_t u_hb    = 0;                                    // P*N*128
    size_t u_xwb   = u_hb + (size_t)P_PATHS * N_NODES * OUT_F;   // P*N*128
    size_t u_eidx2 = u_xwb + (size_t)P_PATHS * N_NODES * OUT_F;  // P*E
    size_t u_Wt    = u_eidx2 + (size_t)P_PATHS * E_EDGES;        // P*IN*OUT
    size_t u_fcwb  = u_Wt + (size_t)P_PATHS * IN_F * OUT_F;      // OUT*OUT

    float* rsout   = ws + off_rsout;
    float* partial = ws + off_partial;
    float* beta    = ws + off_beta;
    int*   ibase   = (int*)(ws + off_i32);
    int*    bstart  = ibase + i_bstart;
    int*    bcursor = ibase + i_bcursor;
    uint_t* bcounts = (uint_t*)(ibase + i_bcounts);
    int*    rsn     = ibase + i_rsn;
    uint_t* dhist   = (uint_t*)(ibase + i_dhist);
    uint_t* ebuf    = (uint_t*)(ibase + i_ebuf);
    ushort_t* ubase = (ushort_t*)(ws + off_u16);
    ushort_t* hb    = ubase + u_hb;
    ushort_t* xwb   = ubase + u_xwb;
    ushort_t* eidx2 = ubase + u_eidx2;
    ushort_t* Wt    = ubase + u_Wt;
    ushort_t* fcwb  = ubase + u_fcwb;

    // only bucket counters accumulate -> zero each call
    hipMemsetAsync(bcounts, 0, (size_t)P_PATHS * NBUCK * sizeof(uint_t), stream);

    deghist_kernel<<<dim3(DSL, 3, P_PATHS), 256, 0, stream>>>(
        src, dst, dhist, bcounts, W, fc_w, Wt, fcwb);
    rsout_bscan_kernel<<<RSB + 1, 1024, 0, stream>>>(dhist, rsout, bcounts, bstart, bcursor);

    gemm_xall_kernel<<<dim3(GBLK, 2), 256, 0, stream>>>(x, Wt, rsout, xwb);
    bscatter_kernel<<<dim3(NCHUNK, P_PATHS), 256, 0, stream>>>(src, dst, bcursor, ebuf);
    blocal_kernel<<<dim3(NBUCK, P_PATHS), 256, 0, stream>>>(ebuf, bstart, eidx2, rsn);
    gather_kernel<<<dim3(N_NODES / 8, P_PATHS), 256, 0, stream>>>(
        xwb, eidx2, rsn, b_conv, (uint4*)hb);
    fc_mfma_kernel<<<GBLK, 256, 0, stream>>>(hb, fcwb, fc_b, partial);

    beta_reduce_kernel<<<1, 1024, 0, stream>>>(partial, att, beta);
    combine_kernel<<<(N_NODES * 64 + 255) / 256, 256, 0, stream>>>(
        (const uint_t*)hb, h_bias, beta, out);
}

// Round 13
// 311.058 us; speedup vs baseline: 1.2115x; 1.1309x over previous
//
#include <hip/hip_runtime.h>
#include <math.h>

#define N_NODES 50000
#define P_PATHS 4
#define E_EDGES 800000
#define IN_F 256
#define OUT_F 128
#define NPB 128                        // nodes per bucket
#define NBUCK 391                      // ceil(N/NPB)
#define NCHUNK 200                     // edge chunks per path
#define CHUNK_E (E_EDGES / NCHUNK)     // 4000
#define GBLK 391                       // row-blocks for gemm/fc (128 rows each)
#define DSL 20                         // edge slices for deg-out histogram
#define QTR 4                          // node quarters
#define Q_N 12500                      // nodes per quarter
#define Q_W 6250                       // packed u32 words per quarter (25KB LDS)
#define BKP 72                         // LDS pitch (u16) for BK=64 gemm tiles
#define FP 136                         // LDS pitch (u16) for K=128 tiles
#define RSB 196                        // rsout blocks in merged rsout+bscan

typedef unsigned short ushort_t;
typedef unsigned int uint_t;
typedef float f32x4 __attribute__((ext_vector_type(4)));
typedef short s16x8 __attribute__((ext_vector_type(8)));

__device__ __forceinline__ ushort_t f2bf(float f) {
    uint_t u = __float_as_uint(f);
    return (ushort_t)((u + 0x7FFFu + ((u >> 16) & 1u)) >> 16);   // RNE
}
__device__ __forceinline__ float bf2f(ushort_t h) {
    return __uint_as_float(((uint_t)h) << 16);
}
__device__ __forceinline__ uint4 pack8(const float4 f0, const float4 f1) {
    uint4 w;
    w.x = (uint_t)f2bf(f0.x) | ((uint_t)f2bf(f0.y) << 16);
    w.y = (uint_t)f2bf(f0.z) | ((uint_t)f2bf(f0.w) << 16);
    w.z = (uint_t)f2bf(f1.x) | ((uint_t)f2bf(f1.y) << 16);
    w.w = (uint_t)f2bf(f1.z) | ((uint_t)f2bf(f1.w) << 16);
    return w;
}
__device__ __forceinline__ float fast_tanh(float v) {
    v = fminf(fmaxf(v, -20.f), 20.f);
    float ex = __expf(2.f * v);
    return (ex - 1.f) / (ex + 1.f);
}
__device__ __forceinline__ void acc8(float4& a0, float4& a1, uint4 w) {
    a0.x += bf2f((ushort_t)w.x);  a0.y += bf2f((ushort_t)(w.x >> 16));
    a0.z += bf2f((ushort_t)w.y);  a0.w += bf2f((ushort_t)(w.y >> 16));
    a1.x += bf2f((ushort_t)w.z);  a1.y += bf2f((ushort_t)(w.z >> 16));
    a1.z += bf2f((ushort_t)w.w);  a1.w += bf2f((ushort_t)(w.w >> 16));
}

// ---------------- prep: W -> Wt bf16 (transposed [p][n][k]), fc_w -> bf16 ----------------
__global__ void prep_kernel(const float* __restrict__ W, const float* __restrict__ fcw,
                            ushort_t* __restrict__ Wt, ushort_t* __restrict__ fcwb)
{
    int idx = blockIdx.x * blockDim.x + threadIdx.x;
    if (idx < P_PATHS * IN_F * OUT_F) {          // 131072
        int p = idx >> 15;
        int r = idx & 32767;
        int k = r >> 7;
        int n = r & 127;
        Wt[((size_t)p << 15) + (size_t)n * IN_F + k] = f2bf(W[idx]);
    }
    if (idx < OUT_F * OUT_F) fcwb[idx] = f2bf(fcw[idx]);
}

// ---------------- deg_out hist (q<QTR, quarter u16) + dst bucket hist (q==QTR) ----------------
__global__ __launch_bounds__(256) void deghist_kernel(const int* __restrict__ src,
                                                      const int* __restrict__ dst,
                                                      uint_t* __restrict__ dhist,
                                                      uint_t* __restrict__ bcounts)
{
    __shared__ uint_t cnt[Q_W];   // 25 KB
    int sl = blockIdx.x, q = blockIdx.y, p = blockIdx.z;
    int t = threadIdx.x;
    if (q == QTR) {
        for (int i = t; i < NBUCK; i += 256) cnt[i] = 0;
        __syncthreads();
        const int4* d4 = (const int4*)(dst + (size_t)p * E_EDGES + (size_t)sl * (E_EDGES / DSL));
        for (int i = t; i < E_EDGES / DSL / 4; i += 256) {
            int4 v = d4[i];
            atomicAdd(&cnt[v.x >> 7], 1u);
            atomicAdd(&cnt[v.y >> 7], 1u);
            atomicAdd(&cnt[v.z >> 7], 1u);
            atomicAdd(&cnt[v.w >> 7], 1u);
        }
        __syncthreads();
        for (int i = t; i < NBUCK; i += 256)
            if (cnt[i]) atomicAdd(&bcounts[p * NBUCK + i], cnt[i]);
        return;
    }
    int nbase = q * Q_N;
    for (int i = t; i < Q_W; i += 256) cnt[i] = 0;
    __syncthreads();
    const int4* s4 = (const int4*)(src + (size_t)p * E_EDGES + (size_t)sl * (E_EDGES / DSL));
    for (int i = t; i < E_EDGES / DSL / 4; i += 256) {
        int4 v = s4[i];
        uint_t r;
        r = (uint_t)(v.x - nbase); if (r < Q_N) atomicAdd(&cnt[r >> 1], 1u << ((r & 1) * 16));
        r = (uint_t)(v.y - nbase); if (r < Q_N) atomicAdd(&cnt[r >> 1], 1u << ((r & 1) * 16));
        r = (uint_t)(v.z - nbase); if (r < Q_N) atomicAdd(&cnt[r >> 1], 1u << ((r & 1) * 16));
        r = (uint_t)(v.w - nbase); if (r < Q_N) atomicAdd(&cnt[r >> 1], 1u << ((r & 1) * 16));
    }
    __syncthreads();
    uint_t* outp = dhist + (((size_t)p * QTR + q) * DSL + sl) * Q_W;
    for (int i = t; i < Q_W; i += 256) outp[i] = cnt[i];
}

// ---------------- merged: blocks 0..RSB-1 -> rsout; block RSB -> bucket scan ----------------
__global__ __launch_bounds__(1024) void rsout_bscan_kernel(const uint_t* __restrict__ dhist,
                                                           float* __restrict__ rsout,
                                                           const uint_t* __restrict__ bcounts,
                                                           int* __restrict__ bstart,
                                                           int* __restrict__ bcursor)
{
    int t = threadIdx.x;
    if (blockIdx.x == RSB) {
        __shared__ int a[2048], b[2048];
        for (int i = t; i < 2048; i += 1024)
            a[i] = (i < P_PATHS * NBUCK) ? (int)bcounts[i] : 0;
        __syncthreads();
        int* pin = a; int* pout = b;
        for (int off = 1; off < 2048; off <<= 1) {
            for (int i = t; i < 2048; i += 1024)
                pout[i] = pin[i] + (i >= off ? pin[i - off] : 0);
            __syncthreads();
            int* tmp = pin; pin = pout; pout = tmp;
        }
        for (int i = t; i < P_PATHS * NBUCK; i += 1024) {
            int st = pin[i] - (int)bcounts[i];
            bstart[i] = st;
            bcursor[i] = st;
        }
        if (t == 0) bstart[P_PATHS * NBUCK] = pin[P_PATHS * NBUCK - 1];
        return;
    }
    int idx = blockIdx.x * 1024 + t;      // over P*QTR*Q_W
    if (idx >= P_PATHS * QTR * Q_W) return;
    int ph = idx / Q_W;
    int w  = idx % Q_W;
    const uint_t* base = dhist + (size_t)ph * DSL * Q_W + w;
    uint_t s = 0;
#pragma unroll
    for (int sl = 0; sl < DSL; ++sl) s += base[(size_t)sl * Q_W];
    int p = ph >> 2, q = ph & 3;
    int node = q * Q_N + 2 * w;
    uint_t c0 = s & 0xFFFFu, c1 = s >> 16;
    rsout[(size_t)p * N_NODES + node]     = rsqrtf((float)(c0 ? c0 : 1u));
    rsout[(size_t)p * N_NODES + node + 1] = rsqrtf((float)(c1 ? c1 : 1u));
}

// ---------------- MFMA GEMM, BK=64 tiles, path-pair per block ----------------
__global__ __launch_bounds__(256) void gemm_xall_kernel(const float* __restrict__ x,
                                                        const ushort_t* __restrict__ Wt,
                                                        const float* __restrict__ rsout,
                                                        ushort_t* __restrict__ xwb)
{
    __shared__ ushort_t As[128 * BKP];   // 18.4 KB
    __shared__ ushort_t Bs[128 * BKP];   // 18.4 KB
    int m0 = blockIdx.x * 128;
    int t = threadIdx.x;
    int wid = t >> 6, lane = t & 63;
    int wr = wid >> 1, wc = wid & 1;
    int srow = t >> 1, h32 = (t & 1) * 32;
    int gr = m0 + srow;
    for (int pp = 0; pp < 2; ++pp) {
        int p = blockIdx.y * 2 + pp;
        const ushort_t* Wp = Wt + ((size_t)p << 15);
        f32x4 acc[4][4] = {};
        for (int kt = 0; kt < 4; ++kt) {
            __syncthreads();   // prior tile reads done
            {   // A: 128x64 fp32 -> bf16
                const float* ap = x + (size_t)gr * IN_F + kt * 64 + h32;
#pragma unroll
                for (int c = 0; c < 4; ++c) {
                    float4 f0 = make_float4(0.f, 0.f, 0.f, 0.f), f1 = f0;
                    if (gr < N_NODES) {
                        f0 = *(const float4*)(ap + c * 8);
                        f1 = *(const float4*)(ap + c * 8 + 4);
                    }
                    *(uint4*)&As[srow * BKP + h32 + c * 8] = pack8(f0, f1);
                }
            }
            {   // B: Wt rows direct u16 copy
                const ushort_t* bp = Wp + (size_t)srow * IN_F + kt * 64 + h32;
#pragma unroll
                for (int c = 0; c < 4; ++c)
                    *(uint4*)&Bs[srow * BKP + h32 + c * 8] = *(const uint4*)(bp + c * 8);
            }
            __syncthreads();
#pragma unroll
            for (int k0 = 0; k0 < 64; k0 += 32) {
                s16x8 aF[4], bF[4];
                int kk = k0 + (lane >> 4) * 8;
#pragma unroll
                for (int m = 0; m < 4; ++m)
                    aF[m] = *(const s16x8*)&As[(wr * 64 + m * 16 + (lane & 15)) * BKP + kk];
#pragma unroll
                for (int n = 0; n < 4; ++n)
                    bF[n] = *(const s16x8*)&Bs[(wc * 64 + n * 16 + (lane & 15)) * BKP + kk];
#pragma unroll
                for (int m = 0; m < 4; ++m)
#pragma unroll
                    for (int n = 0; n < 4; ++n)
                        acc[m][n] = __builtin_amdgcn_mfma_f32_16x16x32_bf16(aF[m], bF[n], acc[m][n], 0, 0, 0);
            }
        }
        ushort_t* xp = xwb + (size_t)p * N_NODES * OUT_F;
        const float* rp = rsout + (size_t)p * N_NODES;
#pragma unroll
        for (int m = 0; m < 4; ++m) {
#pragma unroll
            for (int i = 0; i < 4; ++i) {
                int row = m0 + wr * 64 + m * 16 + (lane >> 4) * 4 + i;
                if (row < N_NODES) {
                    float rs = rp[row];
#pragma unroll
                    for (int n = 0; n < 4; ++n) {
                        int col = wc * 64 + n * 16 + (lane & 15);
                        xp[(size_t)row * OUT_F + col] = f2bf(acc[m][n][i] * rs);
                    }
                }
            }
        }
    }
}

// ---------------- scatter packed edges (src | dloc<<16) into bucket order, all paths ----------------
__global__ __launch_bounds__(256) void bscatter_kernel(const int* __restrict__ src,
                                                       const int* __restrict__ dst,
                                                       int* __restrict__ bcursor,
                                                       uint_t* __restrict__ ebuf)
{
    __shared__ uint_t bh[NBUCK];
    __shared__ uint_t lbase[NBUCK];
    int p = blockIdx.y;
    int t = threadIdx.x;
    int poff = p * E_EDGES;
    int* bcursor_p = bcursor + p * NBUCK;
    uint_t* ebuf_p = ebuf + (size_t)p * E_EDGES;
    for (int i = t; i < NBUCK; i += 256) bh[i] = 0;
    __syncthreads();
    size_t ebase = (size_t)p * E_EDGES + (size_t)blockIdx.x * CHUNK_E;
    const int4* d4 = (const int4*)(dst + ebase);
    const int4* s4 = (const int4*)(src + ebase);
    for (int i = t; i < CHUNK_E / 4; i += 256) {
        int4 v = d4[i];
        atomicAdd(&bh[v.x >> 7], 1u);
        atomicAdd(&bh[v.y >> 7], 1u);
        atomicAdd(&bh[v.z >> 7], 1u);
        atomicAdd(&bh[v.w >> 7], 1u);
    }
    __syncthreads();
    for (int i = t; i < NBUCK; i += 256) {
        uint_t c = bh[i];
        lbase[i] = c ? (uint_t)(atomicAdd(&bcursor_p[i], (int)c) - poff) : 0u;
        bh[i] = 0;     // reuse as local cursor
    }
    __syncthreads();
    for (int i = t; i < CHUNK_E / 4; i += 256) {
        int4 d = d4[i];
        int4 s = s4[i];
        { int bk = d.x >> 7; uint_t pos = lbase[bk] + atomicAdd(&bh[bk], 1u); ebuf_p[pos] = (uint_t)s.x | ((uint_t)(d.x & 127) << 16); }
        { int bk = d.y >> 7; uint_t pos = lbase[bk] + atomicAdd(&bh[bk], 1u); ebuf_p[pos] = (uint_t)s.y | ((uint_t)(d.y & 127) << 16); }
        { int bk = d.z >> 7; uint_t pos = lbase[bk] + atomicAdd(&bh[bk], 1u); ebuf_p[pos] = (uint_t)s.z | ((uint_t)(d.z & 127) << 16); }
        { int bk = d.w >> 7; uint_t pos = lbase[bk] + atomicAdd(&bh[bk], 1u); ebuf_p[pos] = (uint_t)s.w | ((uint_t)(d.w & 127) << 16); }
    }
}

// ---------------- per-bucket local CSR build, all paths ----------------
__global__ __launch_bounds__(256) void blocal_kernel(const uint_t* __restrict__ ebuf,
                                                     const int* __restrict__ bstart,
                                                     ushort_t* __restrict__ eidx2,
                                                     int* __restrict__ rsn)
{
    __shared__ uint_t hist[NPB];
    __shared__ uint_t cur[NPB];
    __shared__ uint_t sa[NPB], sb[NPB];
    int bkt = blockIdx.x;
    int p = blockIdx.y;
    int t = threadIdx.x;
    int poff = p * E_EDGES;
    const uint_t* ebuf_p = ebuf + (size_t)p * E_EDGES;
    ushort_t* eidx2_p = eidx2 + (size_t)p * E_EDGES;
    int* rsn_p = rsn + (size_t)p * (N_NODES + 1);
    if (t < NPB) hist[t] = 0;
    __syncthreads();
    int r0 = bstart[p * NBUCK + bkt] - poff;
    int r1 = bstart[p * NBUCK + bkt + 1] - poff;
    for (int e = r0 + t; e < r1; e += 256)
        atomicAdd(&hist[ebuf_p[e] >> 16], 1u);
    __syncthreads();
    if (t < NPB) sa[t] = hist[t];
    __syncthreads();
    uint_t* pin = sa; uint_t* pout = sb;
    for (int off = 1; off < NPB; off <<= 1) {
        if (t < NPB) pout[t] = pin[t] + (t >= off ? pin[t - off] : 0u);
        __syncthreads();
        uint_t* tmp = pin; pin = pout; pout = tmp;
    }
    if (t < NPB) {
        uint_t ex = pin[t] - hist[t];
        int node = bkt * NPB + t;
        if (node < N_NODES) rsn_p[node] = r0 + (int)ex;
        cur[t] = ex;
    }
    if (bkt == NBUCK - 1 && t == 0) rsn_p[N_NODES] = r1;   // == E_EDGES
    __syncthreads();
    for (int e = r0 + t; e < r1; e += 256) {
        uint_t pk = ebuf_p[e];
        int dl = (int)(pk >> 16);
        uint_t pos = atomicAdd(&cur[dl], 1u);
        eidx2_p[r0 + pos] = (ushort_t)(pk & 0xFFFFu);
    }
}

// ---------------- gather v4: half-wave per node, 2 edges per uint4 load, shfl merge ----------------
__global__ __launch_bounds__(256) void gather_kernel(const ushort_t* __restrict__ xwb,
                                                     const ushort_t* __restrict__ eidx2,
                                                     const int* __restrict__ rsn,
                                                     const float* __restrict__ bconv,
                                                     uint4* __restrict__ hb)   // row = 16 uint4
{
    int hw = threadIdx.x >> 5;          // half-wave 0..7
    int lane = threadIdx.x & 31;
    int sub = lane >> 4;                // which edge of the pair
    int c16 = lane & 15;                // col group: cols 8*c16 .. 8*c16+7
    int p = blockIdx.y;
    int n = blockIdx.x * 8 + hw;
    const int* rsn_p = rsn + (size_t)p * (N_NODES + 1);
    const ushort_t* ei = eidx2 + (size_t)p * E_EDGES;
    int b = rsn_p[n], e = rsn_p[n + 1];
    const uint4* base = (const uint4*)xwb + (size_t)p * N_NODES * 16 + c16;
    float4 a0 = make_float4(0.f, 0.f, 0.f, 0.f);
    float4 a1 = make_float4(0.f, 0.f, 0.f, 0.f);
    int i = b;
    for (; i + 8 <= e; i += 8) {        // 8 edges per iter (4 per sub-stream)
        int s0 = ei[i + sub];
        int s1 = ei[i + 2 + sub];
        int s2 = ei[i + 4 + sub];
        int s3 = ei[i + 6 + sub];
        uint4 w0 = base[(size_t)s0 * 16];
        uint4 w1 = base[(size_t)s1 * 16];
        uint4 w2 = base[(size_t)s2 * 16];
        uint4 w3 = base[(size_t)s3 * 16];
        acc8(a0, a1, w0); acc8(a0, a1, w1); acc8(a0, a1, w2); acc8(a0, a1, w3);
    }
    for (; i + 2 <= e; i += 2) {
        int s = ei[i + sub];
        uint4 w = base[(size_t)s * 16];
        acc8(a0, a1, w);
    }
    if (i < e && sub == 0) {            // odd last edge: lo sub-stream only
        int s = ei[i];
        uint4 w = base[(size_t)s * 16];
        acc8(a0, a1, w);
    }
    // merge the two edge sub-streams (lanes l <-> l^16 hold same cols)
    a0.x += __shfl_xor(a0.x, 16); a0.y += __shfl_xor(a0.y, 16);
    a0.z += __shfl_xor(a0.z, 16); a0.w += __shfl_xor(a0.w, 16);
    a1.x += __shfl_xor(a1.x, 16); a1.y += __shfl_xor(a1.y, 16);
    a1.z += __shfl_xor(a1.z, 16); a1.w += __shfl_xor(a1.w, 16);
    if (sub == 0) {
        int d = e - b;
        float sc = rsqrtf((float)(d > 0 ? d : 1));
        float4 bc0 = *(const float4*)(bconv + (size_t)p * OUT_F + c16 * 8);
        float4 bc1 = *(const float4*)(bconv + (size_t)p * OUT_F + c16 * 8 + 4);
        uint4 o;
        o.x = (uint_t)f2bf(fmaf(a0.x, sc, bc0.x)) | ((uint_t)f2bf(fmaf(a0.y, sc, bc0.y)) << 16);
        o.y = (uint_t)f2bf(fmaf(a0.z, sc, bc0.z)) | ((uint_t)f2bf(fmaf(a0.w, sc, bc0.w)) << 16);
        o.z = (uint_t)f2bf(fmaf(a1.x, sc, bc1.x)) | ((uint_t)f2bf(fmaf(a1.y, sc, bc1.y)) << 16);
        o.w = (uint_t)f2bf(fmaf(a1.z, sc, bc1.z)) | ((uint_t)f2bf(fmaf(a1.w, sc, bc1.w)) << 16);
        hb[((size_t)p * N_NODES + n) * 16 + c16] = o;
    }
}

// ---------------- MFMA fc: ALL paths per block; Bs(fcw) staged once ----------------
__global__ __launch_bounds__(256) void fc_mfma_kernel(const ushort_t* __restrict__ hb,
                                                      const ushort_t* __restrict__ fcwb,
                                                      const float* __restrict__ fcb,
                                                      float* __restrict__ partial)
{
    __shared__ ushort_t As[128 * FP];   // 34 KB
    __shared__ ushort_t Bs[128 * FP];   // 34 KB
    __shared__ float red[2][128];
    int m0 = blockIdx.x * 128;
    int t = threadIdx.x;
    int wid = t >> 6, lane = t & 63;
    int wr = wid >> 1, wc = wid & 1;
    int srow = t >> 1, half = (t & 1) * 16;
    int gr = m0 + srow;
    {   // stage Bs once (fcw[o][k] row-major = [n][k])
#pragma unroll
        for (int c = 0; c < 4; ++c) {
            int kb = c * 32 + half;
            const ushort_t* bp = fcwb + (size_t)srow * OUT_F + kb;
            *(uint4*)&Bs[srow * FP + kb]     = *(const uint4*)(bp);
            *(uint4*)&Bs[srow * FP + kb + 8] = *(const uint4*)(bp + 8);
        }
    }
    for (int p = 0; p < P_PATHS; ++p) {
        __syncthreads();   // prev path reads of As / red done (also covers Bs staging)
        const ushort_t* hp = hb + (size_t)p * N_NODES * OUT_F;
#pragma unroll
        for (int c = 0; c < 4; ++c) {
            int kb = c * 32 + half;
            uint4 w0 = make_uint4(0, 0, 0, 0), w1 = w0;
            if (gr < N_NODES) {
                const ushort_t* ap = hp + (size_t)gr * OUT_F + kb;
                w0 = *(const uint4*)(ap);
                w1 = *(const uint4*)(ap + 8);
            }
            *(uint4*)&As[srow * FP + kb]     = w0;
            *(uint4*)&As[srow * FP + kb + 8] = w1;
        }
        __syncthreads();
        f32x4 acc[4][4] = {};
#pragma unroll
        for (int k0 = 0; k0 < OUT_F; k0 += 32) {
            s16x8 aF[4], bF[4];
            int kk = k0 + (lane >> 4) * 8;
#pragma unroll
            for (int m = 0; m < 4; ++m)
                aF[m] = *(const s16x8*)&As[(wr * 64 + m * 16 + (lane & 15)) * FP + kk];
#pragma unroll
            for (int n = 0; n < 4; ++n)
                bF[n] = *(const s16x8*)&Bs[(wc * 64 + n * 16 + (lane & 15)) * FP + kk];
#pragma unroll
            for (int m = 0; m < 4; ++m)
#pragma unroll
                for (int n = 0; n < 4; ++n)
                    acc[m][n] = __builtin_amdgcn_mfma_f32_16x16x32_bf16(aF[m], bF[n], acc[m][n], 0, 0, 0);
        }
#pragma unroll
        for (int n = 0; n < 4; ++n) {
            int col = wc * 64 + n * 16 + (lane & 15);
            float fb = fcb[col];
            float s = 0.f;
#pragma unroll
            for (int m = 0; m < 4; ++m)
#pragma unroll
                for (int i = 0; i < 4; ++i) {
                    int row = m0 + wr * 64 + m * 16 + (lane >> 4) * 4 + i;
                    if (row < N_NODES) s += fast_tanh(acc[m][n][i] + fb);
                }
            s += __shfl_xor(s, 16);
            s += __shfl_xor(s, 32);
            if (lane < 16) red[wr][col] = s;
        }
        __syncthreads();
        if (t < 128)
            partial[((size_t)p * GBLK + blockIdx.x) * OUT_F + t] = red[0][t] + red[1][t];
    }
}

// ---------------- reduce partials -> sp -> beta softmax ----------------
__global__ __launch_bounds__(512) void beta_reduce_kernel(const float* __restrict__ partial,
                                                          const float* __restrict__ att,
                                                          float* __restrict__ beta)
{
    int t = threadIdx.x;          // 512 = P*128
    int p = t >> 7, c = t & 127;
    float s = 0.f;
    for (int i = 0; i < GBLK; ++i)
        s += partial[((size_t)p * GBLK + i) * OUT_F + c];
    float v = att[p * OUT_F + c] * (s * (1.0f / N_NODES));
    __shared__ float red[512];
    red[t] = v;
    __syncthreads();
    for (int off = 64; off >= 1; off >>= 1) {
        if (c < off) red[t] += red[t + off];
        __syncthreads();
    }
    if (t == 0) {
        float w[P_PATHS], mx = -1e30f;
        for (int q = 0; q < P_PATHS; ++q) { w[q] = red[q * 128]; mx = fmaxf(mx, w[q]); }
        float sum = 0.f;
        for (int q = 0; q < P_PATHS; ++q) { w[q] = expf(w[q] - mx); sum += w[q]; }
        for (int q = 0; q < P_PATHS; ++q) beta[q] = w[q] / sum;
    }
}

// ---------------- out = sum_p beta[p]*h[p] + h_bias ----------------
__global__ void combine_kernel(const uint_t* __restrict__ hb, const float* __restrict__ hbias,
                               const float* __restrict__ beta, float* __restrict__ out)
{
    int idx = blockIdx.x * blockDim.x + threadIdx.x;   // over N*64
    if (idx >= N_NODES * 64) return;
    int n = idx >> 6;
    int w = idx & 63;
    float2 hbv = *(const float2*)(hbias + 2 * w);
    float r0 = hbv.x, r1 = hbv.y;
#pragma unroll
    for (int p = 0; p < P_PATHS; ++p) {
        float bp = beta[p];
        uint_t v = hb[((size_t)p * N_NODES + n) * 64 + w];
        r0 = fmaf(bp, bf2f((ushort_t)v), r0);
        r1 = fmaf(bp, bf2f((ushort_t)(v >> 16)), r1);
    }
    *(float2*)(out + (size_t)n * OUT_F + 2 * w) = make_float2(r0, r1);
}

extern "C" void kernel_launch(void* const* d_in, const int* in_sizes, int n_in,
                              void* d_out, int out_size, void* d_ws, size_t ws_size,
                              hipStream_t stream)
{
    const float* x      = (const float*)d_in[0];
    const float* W      = (const float*)d_in[1];
    const float* b_conv = (const float*)d_in[2];
    const float* att    = (const float*)d_in[3];
    const float* fc_w   = (const float*)d_in[4];
    const float* fc_b   = (const float*)d_in[5];
    const float* h_bias = (const float*)d_in[6];
    const int*   src    = (const int*)d_in[7];
    const int*   dst    = (const int*)d_in[8];
    float* out = (float*)d_out;
    float* ws  = (float*)d_ws;

    // ---- ws layout ----
    size_t off_rsout   = 0;                                            // P*N f32
    size_t off_partial = off_rsout + (size_t)P_PATHS * N_NODES;        // P*GBLK*128 f32
    size_t off_beta    = off_partial + (size_t)P_PATHS * GBLK * OUT_F;
    size_t off_i32     = (off_beta + 4 + 63) & ~(size_t)63;
    // int region (units of int)
    size_t i_bstart  = 0;                                  // P*NBUCK+1 -> pad 1600
    size_t i_bcursor = 1600;                               // P*NBUCK
    size_t i_bcounts = 3200;                               // P*NBUCK
    size_t i_rsn     = 4800;                               // P*(N+1) -> pad 204864
    size_t i_dhist   = 204864;                             // P*QTR*DSL*Q_W = 2,000,000
    size_t i_ebuf    = i_dhist + (size_t)P_PATHS * QTR * DSL * Q_W;   // P*E
    size_t n_ints    = i_ebuf + (size_t)P_PATHS * E_EDGES;
    size_t off_u16   = off_i32 + ((n_ints + 63) & ~(size_t)63);
    // ushort region (units of ushort)
    size_t u_hb    = 0;                                    // P*N*128
    size_t u_xwb   = u_hb + (size_t)P_PATHS * N_NODES * OUT_F;   // P*N*128
    size_t u_eidx2 = u_xwb + (size_t)P_PATHS * N_NODES * OUT_F;  // P*E
    size_t u_Wt    = u_eidx2 + (size_t)P_PATHS * E_EDGES;        // P*IN*OUT
    size_t u_fcwb  = u_Wt + (size_t)P_PATHS * IN_F * OUT_F;      // OUT*OUT

    float* rsout   = ws + off_rsout;
    float* partial = ws + off_partial;
    float* beta    = ws + off_beta;
    int*   ibase   = (int*)(ws + off_i32);
    int*    bstart  = ibase + i_bstart;
    int*    bcursor = ibase + i_bcursor;
    uint_t* bcounts = (uint_t*)(ibase + i_bcounts);
    int*    rsn     = ibase + i_rsn;
    uint_t* dhist   = (uint_t*)(ibase + i_dhist);
    uint_t* ebuf    = (uint_t*)(ibase + i_ebuf);
    ushort_t* ubase = (ushort_t*)(ws + off_u16);
    ushort_t* hb    = ubase + u_hb;
    ushort_t* xwb   = ubase + u_xwb;
    ushort_t* eidx2 = ubase + u_eidx2;
    ushort_t* Wt    = ubase + u_Wt;
    ushort_t* fcwb  = ubase + u_fcwb;

    // only bucket counters accumulate -> zero each call
    hipMemsetAsync(bcounts, 0, (size_t)P_PATHS * NBUCK * sizeof(uint_t), stream);

    prep_kernel<<<(P_PATHS * IN_F * OUT_F + 255) / 256, 256, 0, stream>>>(W, fc_w, Wt, fcwb);
    deghist_kernel<<<dim3(DSL, QTR + 1, P_PATHS), 256, 0, stream>>>(src, dst, dhist, bcounts);
    rsout_bscan_kernel<<<RSB + 1, 1024, 0, stream>>>(dhist, rsout, bcounts, bstart, bcursor);

    gemm_xall_kernel<<<dim3(GBLK, 2), 256, 0, stream>>>(x, Wt, rsout, xwb);
    bscatter_kernel<<<dim3(NCHUNK, P_PATHS), 256, 0, stream>>>(src, dst, bcursor, ebuf);
    blocal_kernel<<<dim3(NBUCK, P_PATHS), 256, 0, stream>>>(ebuf, bstart, eidx2, rsn);
    gather_kernel<<<dim3(N_NODES / 8, P_PATHS), 256, 0, stream>>>(
        xwb, eidx2, rsn, b_conv, (uint4*)hb);
    fc_mfma_kernel<<<GBLK, 256, 0, stream>>>(hb, fcwb, fc_b, partial);

    beta_reduce_kernel<<<1, 512, 0, stream>>>(partial, att, beta);
    combine_kernel<<<(N_NODES * 64 + 255) / 256, 256, 0, stream>>>(
        (const uint_t*)hb, h_bias, beta, out);
}